// Round 2
// baseline (361.808 us; speedup 1.0000x reference)
//
#include <hip/hip_runtime.h>

#define N 32
#define C 256
#define HW 1024
#define S 64
#define LOG2E 1.4426950408889634f

typedef _Float16 f16;
typedef _Float16 f16x8 __attribute__((ext_vector_type(8)));
typedef float f32x4 __attribute__((ext_vector_type(4)));

#define MFMA(a, b, c) __builtin_amdgcn_mfma_f32_16x16x32_f16(a, b, c, 0, 0, 0)
#define EXP2(x) exp2f(x)

// ---------- weight conversion ----------
__global__ void k_prep(const float* Ws1, const float* Ws11, const float* Wg,
                       f16* Wf, f16* Wgf) {
    int i = blockIdx.x * 256 + threadIdx.x;   // grid covers 65536
    if (i < S * C) { Wf[i] = (f16)Ws1[i]; Wf[S * C + i] = (f16)Ws11[i]; }
    Wgf[i] = (f16)Wg[i];
}

// ---------- channel-max pools + fp16 copy of seg ----------
__global__ void k_pool(const float* seg, const float* edge, f16* segf,
                       float* a2, float* bq, const float* ws2, const float* bs2,
                       const float* ws3, const float* bs3) {
    int n = blockIdx.x >> 2;
    int p = ((blockIdx.x & 3) << 8) + threadIdx.x;
    const float* sp = seg + (size_t)n * C * HW + p;
    const float* ep = edge + (size_t)n * C * HW + p;
    f16* fp = segf + (size_t)n * C * HW + p;
    float ms = -3e38f, mp = -3e38f;
    for (int c = 0; c < C; c++) {
        float s = sp[(size_t)c * HW];
        float eg = ep[(size_t)c * HW];
        fp[(size_t)c * HW] = (f16)s;
        ms = fmaxf(ms, s);
        mp = fmaxf(mp, s * eg);
    }
    a2[(size_t)n * HW + p] = (mp * ws3[0] + bs3[0]) * LOG2E;  // edge_mm * log2e
    bq[(size_t)n * HW + p] = ms * ws2[0] + bs2[0];            // seg_ss
}

// ---------- per-(n,c) mean over hw ----------
__global__ void k_mean(const float* seg, float* mean) {
    int n = blockIdx.x >> 8, c = blockIdx.x & 255;
    const float* sp = seg + ((size_t)n * C + c) * HW;
    int t = threadIdx.x;
    float s = sp[t] + sp[t + 256] + sp[t + 512] + sp[t + 768];
    for (int o = 32; o; o >>= 1) s += __shfl_down(s, o);
    __shared__ float red[4];
    if ((t & 63) == 0) red[t >> 6] = s;
    __syncthreads();
    if (t == 0) mean[n * C + c] = (red[0] + red[1] + red[2] + red[3]) * (1.0f / HW);
}

// ---------- ch_att = relu(mean @ Wmlp^T + bmlp) ----------
__global__ void k_chatt(const float* mean, const float* Wmlp, const float* bmlp,
                        float* chat) {
    int n = blockIdx.x, s = threadIdx.x;
    __shared__ float m[C];
    for (int i = s; i < C; i += 64) m[i] = mean[n * C + i];
    __syncthreads();
    float acc = 0.f;
    const float* wr = Wmlp + (size_t)s * C;
    for (int c = 0; c < C; c++) acc += m[c] * wr[c];
    chat[n * S + s] = fmaxf(acc + bmlp[s], 0.f);
}

// ---------- projections: seg_s (rows 0..63) & seg_c (rows 64..127) ----------
__global__ void __launch_bounds__(256) k_proj(const f16* segf, const f16* Wf,
        const float* bs1, const float* bs11, f16* segs16, f16* segc) {
    int n = blockIdx.y;
    int q0 = blockIdx.x * 64;
    __shared__ f16 sT[64][264];   // [q][c], stride 264 f16 (16B-aligned rows)
    const f16* sb = segf + (size_t)n * C * HW + q0;
    int tid = threadIdx.x;
    for (int idx = tid; idx < 64 * (C / 2); idx += 256) {
        int q = idx & 63, cc = (idx >> 6) << 1;
        sT[q][cc]     = sb[(size_t)cc * HW + q];
        sT[q][cc + 1] = sb[(size_t)(cc + 1) * HW + q];
    }
    __syncthreads();
    int lane = tid & 63, wv = tid >> 6;
    int lm = lane & 15, lg = lane >> 4;
    f32x4 acc[2][4] = {};
    for (int ck = 0; ck < 8; ck++) {
        int c0 = ck * 32;
        f16x8 a0 = *(const f16x8*)(Wf + (size_t)(wv * 32 + lm) * C + c0 + lg * 8);
        f16x8 a1 = *(const f16x8*)(Wf + (size_t)(wv * 32 + 16 + lm) * C + c0 + lg * 8);
        for (int j = 0; j < 4; j++) {
            f16x8 b = *(const f16x8*)&sT[j * 16 + lm][c0 + lg * 8];
            acc[0][j] = MFMA(a0, b, acc[0][j]);
            acc[1][j] = MFMA(a1, b, acc[1][j]);
        }
    }
    for (int i = 0; i < 2; i++)
        for (int rr = 0; rr < 4; rr++) {
            int row = wv * 32 + i * 16 + lg * 4 + rr;
            float bias = (row < S) ? bs1[row] : bs11[row - S];
            for (int j = 0; j < 4; j++) {
                int q = q0 + j * 16 + lm;
                float v = acc[i][j][rr] + bias;
                if (row < S) segs16[((size_t)n * S + row) * HW + q] = (f16)v;
                else         segc[((size_t)n * S + (row - S)) * HW + q] = (f16)v;
            }
        }
}

// ---------- dp2[p] = (theta[p,:]·ch_att)*log2e, e[q], dp2 max/min ----------
__global__ void k_dp(const f16* segs16, const float* chat, float* dp2, float* e_,
                     float* dpmm) {
    int n = blockIdx.x, t = threadIdx.x;
    __shared__ float cA[S];
    __shared__ float rmx[4], rmn[4];
    if (t < S) cA[t] = chat[n * S + t];
    __syncthreads();
    const f16* ss = segs16 + (size_t)n * S * HW;
    float mx = -3e38f, mn = 3e38f;
    for (int p = t; p < HW; p += 256) {
        // theta[p,t] = seg_s[p>>4][64*(p&15)+t]  (flat reshape!)
        const f16* base = ss + (size_t)(p >> 4) * HW + ((p & 15) << 6);
        float acc = 0.f;
        for (int tt = 0; tt < S; tt += 8) {
            f16x8 v = *(const f16x8*)(base + tt);
            for (int j = 0; j < 8; j++) acc += (float)v[j] * cA[tt + j];
        }
        float d2 = acc * LOG2E;
        dp2[(size_t)n * HW + p] = d2;
        mx = fmaxf(mx, d2); mn = fminf(mn, d2);
    }
    for (int q = t; q < HW; q += 256) {
        float acc = 0.f;
        for (int tt = 0; tt < S; tt++) acc += cA[tt] * (float)ss[(size_t)tt * HW + q];
        e_[(size_t)n * HW + q] = acc;
    }
    for (int o = 32; o; o >>= 1) {
        mx = fmaxf(mx, __shfl_down(mx, o));
        mn = fminf(mn, __shfl_down(mn, o));
    }
    if ((t & 63) == 0) { rmx[t >> 6] = mx; rmn[t >> 6] = mn; }
    __syncthreads();
    if (t == 0) {
        dpmm[n * 2]     = fmaxf(fmaxf(rmx[0], rmx[1]), fmaxf(rmx[2], rmx[3]));
        dpmm[n * 2 + 1] = fminf(fminf(rmn[0], rmn[1]), fminf(rmn[2], rmn[3]));
    }
}

// ---------- sim_c softmax stats (rank-1 logits) ----------
__global__ void k_zc(const float* dp2, const float* e_, const float* dpmm,
                     float* Mc2, float* iZc) {
    int n = blockIdx.x >> 2;
    int q = ((blockIdx.x & 3) << 8) + threadIdx.x;
    __shared__ float d[HW];
    for (int i = threadIdx.x; i < HW; i += 256) d[i] = dp2[(size_t)n * HW + i];
    __syncthreads();
    float eq = e_[(size_t)n * HW + q];
    float m = (eq > 0.f) ? eq * dpmm[n * 2] : eq * dpmm[n * 2 + 1];
    float z = 0.f;
    for (int p = 0; p < HW; p++) z += EXP2(d[p] * eq - m);
    Mc2[(size_t)n * HW + q] = m;
    iZc[(size_t)n * HW + q] = 1.f / z;
}

// ---------- sim_s softmax stats: online (m,l) over p per column q ----------
__global__ void __launch_bounds__(512) k_sstats(const f16* segc, const float* a2,
        const float* bq, float* Ms2, float* iZs) {
    int n = blockIdx.y, q0 = blockIdx.x * 128;
    __shared__ f16 bT[128][72];     // [q][t]
    __shared__ float a2s[HW];
    const f16* cb = segc + (size_t)n * S * HW;
    int tid = threadIdx.x;
    for (int idx = tid; idx < 128 * (S / 2); idx += 512) {
        int q = idx & 127, th = (idx >> 7) << 1;
        bT[q][th]     = cb[(size_t)th * HW + q0 + q];
        bT[q][th + 1] = cb[(size_t)(th + 1) * HW + q0 + q];
    }
    for (int i = tid; i < HW; i += 512) a2s[i] = a2[(size_t)n * HW + i];
    __syncthreads();
    int w = tid >> 6, lane = tid & 63, lm = lane & 15, lg = lane >> 4;
    f16x8 b0 = *(const f16x8*)&bT[w * 16 + lm][lg * 8];
    f16x8 b1 = *(const f16x8*)&bT[w * 16 + lm][32 + lg * 8];
    float bqv = bq[(size_t)n * HW + q0 + w * 16 + lm];
    float m = -3e38f, l = 0.f;
    for (int pf = 0; pf < 64; pf++) {
        // sigma_T[p][t] = segc flat-reshaped: contiguous t at p*64
        f16x8 a0 = *(const f16x8*)(cb + (size_t)(pf * 16 + lm) * S + lg * 8);
        f16x8 a1 = *(const f16x8*)(cb + (size_t)(pf * 16 + lm) * S + 32 + lg * 8);
        f32x4 sg = {};
        sg = MFMA(a0, b0, sg);
        sg = MFMA(a1, b1, sg);
        float sc[4];
        float fm = -3e38f;
        for (int rr = 0; rr < 4; rr++) {
            float av = a2s[pf * 16 + lg * 4 + rr];
            sc[rr] = av * bqv * sg[rr];
            fm = fmaxf(fm, sc[rr]);
        }
        fm = fmaxf(fm, __shfl_xor(fm, 16));
        fm = fmaxf(fm, __shfl_xor(fm, 32));
        float fl = 0.f;
        for (int rr = 0; rr < 4; rr++) fl += EXP2(sc[rr] - fm);
        fl += __shfl_xor(fl, 16);
        fl += __shfl_xor(fl, 32);
        float nm = fmaxf(m, fm);
        l = l * EXP2(m - nm) + fl * EXP2(fm - nm);
        m = nm;
    }
    if (lg == 0) {
        Ms2[(size_t)n * HW + q0 + w * 16 + lm] = m;
        iZs[(size_t)n * HW + q0 + w * 16 + lm] = 1.f / l;
    }
}

// ---------- fused: sigma tile -> weights -> seg_sim, output transposed f16 ----------
__global__ void __launch_bounds__(512) k_fused(const f16* segf, const f16* segc,
        const float* dp2, const float* e_, const float* a2, const float* bq,
        const float* Mc2, const float* iZc, const float* Ms2, const float* iZs,
        f16* simT) {
    int n = blockIdx.y, q0 = blockIdx.x * 128;
    __shared__ f16 bT[128][72];     // segc^T tile [q][t]
    __shared__ f16 wT[128][72];     // weight tile [q][p - p0]
    __shared__ float dp2s[HW], a2s[HW];
    const f16* cb = segc + (size_t)n * S * HW;
    const f16* sb = segf + (size_t)n * C * HW;
    int tid = threadIdx.x;
    for (int idx = tid; idx < 128 * (S / 2); idx += 512) {
        int q = idx & 127, th = (idx >> 7) << 1;
        bT[q][th]     = cb[(size_t)th * HW + q0 + q];
        bT[q][th + 1] = cb[(size_t)(th + 1) * HW + q0 + q];
    }
    for (int i = tid; i < HW; i += 512) {
        dp2s[i] = dp2[(size_t)n * HW + i];
        a2s[i]  = a2[(size_t)n * HW + i];
    }
    __syncthreads();
    int w = tid >> 6, lane = tid & 63, lm = lane & 15, lg = lane >> 4;
    int pw = w & 3;       // stage-1 p-frag; stage-2 c quarter
    int qh = w >> 2;      // q half
    f16x8 b1[4][2];
    float ev[4], bqv[4], mcv[4], izcv[4], msv[4], izsv[4];
    for (int qf = 0; qf < 4; qf++) {
        int ql = qh * 64 + qf * 16 + lm;
        b1[qf][0] = *(const f16x8*)&bT[ql][lg * 8];
        b1[qf][1] = *(const f16x8*)&bT[ql][32 + lg * 8];
        size_t gq = (size_t)n * HW + q0 + ql;
        ev[qf] = e_[gq];  bqv[qf] = bq[gq];
        mcv[qf] = Mc2[gq]; izcv[qf] = iZc[gq];
        msv[qf] = Ms2[gq]; izsv[qf] = iZs[gq];
    }
    f32x4 acc[4][4] = {};
    for (int chk = 0; chk < 16; chk++) {
        int p0 = chk * 64;
        f16x8 sa0 = *(const f16x8*)(cb + (size_t)(p0 + pw * 16 + lm) * S + lg * 8);
        f16x8 sa1 = *(const f16x8*)(cb + (size_t)(p0 + pw * 16 + lm) * S + 32 + lg * 8);
        float d2r[4], avr[4];
        for (int rr = 0; rr < 4; rr++) {
            d2r[rr] = dp2s[p0 + pw * 16 + lg * 4 + rr];
            avr[rr] = a2s[p0 + pw * 16 + lg * 4 + rr];
        }
        for (int qf = 0; qf < 4; qf++) {
            f32x4 sg = {};
            sg = MFMA(sa0, b1[qf][0], sg);
            sg = MFMA(sa1, b1[qf][1], sg);
            float wgt[4];
            for (int rr = 0; rr < 4; rr++) {
                float wc  = EXP2(d2r[rr] * ev[qf] - mcv[qf]) * izcv[qf];
                float wsv = EXP2(avr[rr] * bqv[qf] * sg[rr] - msv[qf]) * izsv[qf];
                wgt[rr] = wc + wsv;
            }
            int ql = qh * 64 + qf * 16 + lm;
            int pp = pw * 16 + lg * 4;
            union { f16 h[2]; unsigned u; } c0u, c1u;
            c0u.h[0] = (f16)wgt[0]; c0u.h[1] = (f16)wgt[1];
            c1u.h[0] = (f16)wgt[2]; c1u.h[1] = (f16)wgt[3];
            *(unsigned*)&wT[ql][pp]     = c0u.u;
            *(unsigned*)&wT[ql][pp + 2] = c1u.u;
        }
        __syncthreads();
        f16x8 a2f[4][2], b2f[4][2];
        for (int cf = 0; cf < 4; cf++) {
            int crow = pw * 64 + cf * 16 + lm;
            a2f[cf][0] = *(const f16x8*)(sb + (size_t)crow * HW + p0 + lg * 8);
            a2f[cf][1] = *(const f16x8*)(sb + (size_t)crow * HW + p0 + 32 + lg * 8);
        }
        for (int qf = 0; qf < 4; qf++) {
            int ql = qh * 64 + qf * 16 + lm;
            b2f[qf][0] = *(const f16x8*)&wT[ql][lg * 8];
            b2f[qf][1] = *(const f16x8*)&wT[ql][32 + lg * 8];
        }
        for (int cf = 0; cf < 4; cf++)
            for (int qf = 0; qf < 4; qf++) {
                acc[cf][qf] = MFMA(a2f[cf][0], b2f[qf][0], acc[cf][qf]);
                acc[cf][qf] = MFMA(a2f[cf][1], b2f[qf][1], acc[cf][qf]);
            }
        __syncthreads();
    }
    for (int cf = 0; cf < 4; cf++)
        for (int qf = 0; qf < 4; qf++) {
            int crow = pw * 64 + cf * 16 + lg * 4;
            size_t qrow = (size_t)n * HW + q0 + qh * 64 + qf * 16 + lm;
            union { f16 h[2]; unsigned u; } c0u, c1u;
            c0u.h[0] = (f16)acc[cf][qf][0]; c0u.h[1] = (f16)acc[cf][qf][1];
            c1u.h[0] = (f16)acc[cf][qf][2]; c1u.h[1] = (f16)acc[cf][qf][3];
            *(unsigned*)(simT + qrow * C + crow)     = c0u.u;
            *(unsigned*)(simT + qrow * C + crow + 2) = c1u.u;
        }
}

// ---------- out = relu(Wg @ seg_sim + bg) + 2*seg_ori ----------
__global__ void __launch_bounds__(512) k_out(const f16* Wgf, const f16* simT,
        const float* bg, const float* seg, float* out) {
    int n = blockIdx.y, q0 = blockIdx.x * 128;
    int tid = threadIdx.x, w = tid >> 6, lane = tid & 63, lm = lane & 15, lg = lane >> 4;
    int ow = (w & 3) * 64, qh = (w >> 2) * 64;
    f32x4 acc[4][4] = {};
    for (int ck = 0; ck < 8; ck++) {
        int c0 = ck * 32;
        f16x8 af[4], bf[4];
        for (int of = 0; of < 4; of++)
            af[of] = *(const f16x8*)(Wgf + (size_t)(ow + of * 16 + lm) * C + c0 + lg * 8);
        for (int qf = 0; qf < 4; qf++)
            bf[qf] = *(const f16x8*)(simT + ((size_t)n * HW + q0 + qh + qf * 16 + lm) * C + c0 + lg * 8);
        for (int of = 0; of < 4; of++)
            for (int qf = 0; qf < 4; qf++)
                acc[of][qf] = MFMA(af[of], bf[qf], acc[of][qf]);
    }
    for (int of = 0; of < 4; of++)
        for (int rr = 0; rr < 4; rr++) {
            int o = ow + of * 16 + lg * 4 + rr;
            float bgv = bg[o];
            for (int qf = 0; qf < 4; qf++) {
                int q = q0 + qh + qf * 16 + lm;
                size_t ix = ((size_t)n * C + o) * HW + q;
                out[ix] = fmaxf(acc[of][qf][rr] + bgv, 0.f) + 2.f * seg[ix];
            }
        }
}

extern "C" void kernel_launch(void* const* d_in, const int* in_sizes, int n_in,
                              void* d_out, int out_size, void* d_ws, size_t ws_size,
                              hipStream_t stream) {
    const float* seg  = (const float*)d_in[0];
    const float* edge = (const float*)d_in[1];
    const float* Ws1  = (const float*)d_in[2];
    const float* bs1  = (const float*)d_in[3];
    const float* Ws11 = (const float*)d_in[4];
    const float* bs11 = (const float*)d_in[5];
    const float* Wmlp = (const float*)d_in[6];
    const float* bmlp = (const float*)d_in[7];
    const float* ws2  = (const float*)d_in[8];
    const float* bs2  = (const float*)d_in[9];
    const float* ws3  = (const float*)d_in[10];
    const float* bs3  = (const float*)d_in[11];
    const float* Wg   = (const float*)d_in[12];
    const float* bg   = (const float*)d_in[13];
    float* out = (float*)d_out;
    char* wsb = (char*)d_ws;

    f16*   segf   = (f16*)(wsb);                   // 16777216 B
    f16*   segc   = (f16*)(wsb + 16777216);        //  4194304 B
    f16*   segs16 = (f16*)(wsb + 20971520);        //  4194304 B
    f16*   simT   = (f16*)(wsb + 25165824);        // 16777216 B
    f16*   Wf     = (f16*)(wsb + 41943040);        //    65536 B
    f16*   Wgf    = (f16*)(wsb + 42008576);        //   131072 B
    float* mean   = (float*)(wsb + 42139648);      //    32768 B
    float* chat   = (float*)(wsb + 42172416);      //     8192 B
    float* dp2    = (float*)(wsb + 42180608);      //   131072 B
    float* e_     = (float*)(wsb + 42311680);
    float* a2     = (float*)(wsb + 42442752);
    float* bq     = (float*)(wsb + 42573824);
    float* Mc2    = (float*)(wsb + 42704896);
    float* iZc    = (float*)(wsb + 42835968);
    float* Ms2    = (float*)(wsb + 42967040);
    float* iZs    = (float*)(wsb + 43098112);
    float* dpmm   = (float*)(wsb + 43229184);      //      256 B

    k_prep<<<256, 256, 0, stream>>>(Ws1, Ws11, Wg, Wf, Wgf);
    k_pool<<<128, 256, 0, stream>>>(seg, edge, segf, a2, bq, ws2, bs2, ws3, bs3);
    k_mean<<<8192, 256, 0, stream>>>(seg, mean);
    k_chatt<<<32, 64, 0, stream>>>(mean, Wmlp, bmlp, chat);
    k_proj<<<dim3(16, 32), 256, 0, stream>>>(segf, Wf, bs1, bs11, segs16, segc);
    k_dp<<<32, 256, 0, stream>>>(segs16, chat, dp2, e_, dpmm);
    k_zc<<<128, 256, 0, stream>>>(dp2, e_, dpmm, Mc2, iZc);
    k_sstats<<<dim3(8, 32), 512, 0, stream>>>(segc, a2, bq, Ms2, iZs);
    k_fused<<<dim3(8, 32), 512, 0, stream>>>(segf, segc, dp2, e_, a2, bq,
                                             Mc2, iZc, Ms2, iZs, simT);
    k_out<<<dim3(8, 32), 512, 0, stream>>>(Wgf, simT, bg, seg, out);
}

// Round 3
// 346.469 us; speedup vs baseline: 1.0443x; 1.0443x over previous
//
#include <hip/hip_runtime.h>

#define N 32
#define C 256
#define HW 1024
#define S 64
#define LOG2E 1.4426950408889634f

typedef _Float16 f16;
typedef _Float16 f16x8 __attribute__((ext_vector_type(8)));
typedef float f32x4 __attribute__((ext_vector_type(4)));

#define MFMA(a, b, c) __builtin_amdgcn_mfma_f32_16x16x32_f16(a, b, c, 0, 0, 0)
#define EXP2(x) exp2f(x)

// ---------- weight conversion ----------
__global__ void k_prep(const float* Ws1, const float* Ws11, const float* Wg,
                       f16* Wf, f16* Wgf) {
    int i = blockIdx.x * 256 + threadIdx.x;   // grid covers 65536
    if (i < S * C) { Wf[i] = (f16)Ws1[i]; Wf[S * C + i] = (f16)Ws11[i]; }
    Wgf[i] = (f16)Wg[i];
}

// ---------- channel-max pools + fp16 copy of seg ----------
__global__ void k_pool(const float* seg, const float* edge, f16* segf,
                       float* a2, float* bq, const float* ws2, const float* bs2,
                       const float* ws3, const float* bs3) {
    int n = blockIdx.x >> 2;
    int p = ((blockIdx.x & 3) << 8) + threadIdx.x;
    const float* sp = seg + (size_t)n * C * HW + p;
    const float* ep = edge + (size_t)n * C * HW + p;
    f16* fp = segf + (size_t)n * C * HW + p;
    float ms = -3e38f, mp = -3e38f;
    for (int c = 0; c < C; c++) {
        float s = sp[(size_t)c * HW];
        float eg = ep[(size_t)c * HW];
        fp[(size_t)c * HW] = (f16)s;
        ms = fmaxf(ms, s);
        mp = fmaxf(mp, s * eg);
    }
    a2[(size_t)n * HW + p] = (mp * ws3[0] + bs3[0]) * LOG2E;  // edge_mm * log2e
    bq[(size_t)n * HW + p] = ms * ws2[0] + bs2[0];            // seg_ss
}

// ---------- per-(n,c) mean over hw (reads f16 copy) ----------
__global__ void k_mean(const f16* segf, float* mean) {
    int n = blockIdx.x >> 8, c = blockIdx.x & 255;
    const f16* sp = segf + ((size_t)n * C + c) * HW;
    int t = threadIdx.x;
    float s = (float)sp[t] + (float)sp[t + 256] + (float)sp[t + 512] + (float)sp[t + 768];
    for (int o = 32; o; o >>= 1) s += __shfl_down(s, o);
    __shared__ float red[4];
    if ((t & 63) == 0) red[t >> 6] = s;
    __syncthreads();
    if (t == 0) mean[n * C + c] = (red[0] + red[1] + red[2] + red[3]) * (1.0f / HW);
}

// ---------- ch_att = relu(mean @ Wmlp^T + bmlp) ----------
__global__ void k_chatt(const float* mean, const float* Wmlp, const float* bmlp,
                        float* chat) {
    int n = blockIdx.x, s = threadIdx.x;
    __shared__ float m[C];
    for (int i = s; i < C; i += 64) m[i] = mean[n * C + i];
    __syncthreads();
    float acc = 0.f;
    const float* wr = Wmlp + (size_t)s * C;
    for (int c = 0; c < C; c++) acc += m[c] * wr[c];
    chat[n * S + s] = fmaxf(acc + bmlp[s], 0.f);
}

// ---------- projections: seg_s (rows 0..63) & seg_c (rows 64..127) ----------
__global__ void __launch_bounds__(256) k_proj(const f16* segf, const f16* Wf,
        const float* bs1, const float* bs11, f16* segs16, f16* segc) {
    int n = blockIdx.y;
    int q0 = blockIdx.x * 64;
    __shared__ f16 sT[64][264];   // [q][c]
    const f16* sb = segf + (size_t)n * C * HW + q0;
    int tid = threadIdx.x;
    for (int idx = tid; idx < 64 * (C / 2); idx += 256) {
        int q = idx & 63, cc = (idx >> 6) << 1;
        sT[q][cc]     = sb[(size_t)cc * HW + q];
        sT[q][cc + 1] = sb[(size_t)(cc + 1) * HW + q];
    }
    __syncthreads();
    int lane = tid & 63, wv = tid >> 6;
    int lm = lane & 15, lg = lane >> 4;
    f32x4 acc[2][4] = {};
    for (int ck = 0; ck < 8; ck++) {
        int c0 = ck * 32;
        f16x8 a0 = *(const f16x8*)(Wf + (size_t)(wv * 32 + lm) * C + c0 + lg * 8);
        f16x8 a1 = *(const f16x8*)(Wf + (size_t)(wv * 32 + 16 + lm) * C + c0 + lg * 8);
        for (int j = 0; j < 4; j++) {
            f16x8 b = *(const f16x8*)&sT[j * 16 + lm][c0 + lg * 8];
            acc[0][j] = MFMA(a0, b, acc[0][j]);
            acc[1][j] = MFMA(a1, b, acc[1][j]);
        }
    }
    for (int i = 0; i < 2; i++)
        for (int rr = 0; rr < 4; rr++) {
            int row = wv * 32 + i * 16 + lg * 4 + rr;
            float bias = (row < S) ? bs1[row] : bs11[row - S];
            for (int j = 0; j < 4; j++) {
                int q = q0 + j * 16 + lm;
                float v = acc[i][j][rr] + bias;
                if (row < S) segs16[((size_t)n * S + row) * HW + q] = (f16)v;
                else         segc[((size_t)n * S + (row - S)) * HW + q] = (f16)v;
            }
        }
}

// ---------- dp2[p] = (theta[p,:]·ch_att)*log2e, e[q], dp2 max/min ----------
__global__ void k_dp(const f16* segs16, const float* chat, float* dp2, float* e_,
                     float* dpmm) {
    int n = blockIdx.x, t = threadIdx.x;
    __shared__ float cA[S];
    __shared__ float rmx[4], rmn[4];
    if (t < S) cA[t] = chat[n * S + t];
    __syncthreads();
    const f16* ss = segs16 + (size_t)n * S * HW;
    float mx = -3e38f, mn = 3e38f;
    for (int p = t; p < HW; p += 256) {
        // theta[p,t] = seg_s[p>>4][64*(p&15)+t]  (flat reshape!)
        const f16* base = ss + (size_t)(p >> 4) * HW + ((p & 15) << 6);
        float acc = 0.f;
        for (int tt = 0; tt < S; tt += 8) {
            f16x8 v = *(const f16x8*)(base + tt);
            for (int j = 0; j < 8; j++) acc += (float)v[j] * cA[tt + j];
        }
        float d2 = acc * LOG2E;
        dp2[(size_t)n * HW + p] = d2;
        mx = fmaxf(mx, d2); mn = fminf(mn, d2);
    }
    for (int q = t; q < HW; q += 256) {
        float acc = 0.f;
        for (int tt = 0; tt < S; tt++) acc += cA[tt] * (float)ss[(size_t)tt * HW + q];
        e_[(size_t)n * HW + q] = acc;
    }
    for (int o = 32; o; o >>= 1) {
        mx = fmaxf(mx, __shfl_down(mx, o));
        mn = fminf(mn, __shfl_down(mn, o));
    }
    if ((t & 63) == 0) { rmx[t >> 6] = mx; rmn[t >> 6] = mn; }
    __syncthreads();
    if (t == 0) {
        dpmm[n * 2]     = fmaxf(fmaxf(rmx[0], rmx[1]), fmaxf(rmx[2], rmx[3]));
        dpmm[n * 2 + 1] = fminf(fminf(rmn[0], rmn[1]), fminf(rmn[2], rmn[3]));
    }
}

// ---------- sim_c softmax stats (rank-1 logits) ----------
__global__ void k_zc(const float* dp2, const float* e_, const float* dpmm,
                     float* Mc2, float* iZc) {
    int n = blockIdx.x >> 2;
    int q = ((blockIdx.x & 3) << 8) + threadIdx.x;
    __shared__ float d[HW];
    for (int i = threadIdx.x; i < HW; i += 256) d[i] = dp2[(size_t)n * HW + i];
    __syncthreads();
    float eq = e_[(size_t)n * HW + q];
    float m = (eq > 0.f) ? eq * dpmm[n * 2] : eq * dpmm[n * 2 + 1];
    float z = 0.f;
    for (int p = 0; p < HW; p++) z += EXP2(d[p] * eq - m);
    Mc2[(size_t)n * HW + q] = m;
    iZc[(size_t)n * HW + q] = 1.f / z;
}

// ---------- sim_s softmax stats: online (m,l) over p per column q ----------
__global__ void __launch_bounds__(512) k_sstats(const f16* segc, const float* a2,
        const float* bq, float* Ms2, float* iZs) {
    int n = blockIdx.y, q0 = blockIdx.x * 128;
    __shared__ f16 bT[128][72];     // [q][t]
    __shared__ float a2s[HW];
    const f16* cb = segc + (size_t)n * S * HW;
    int tid = threadIdx.x;
    for (int idx = tid; idx < 128 * (S / 2); idx += 512) {
        int q = idx & 127, th = (idx >> 7) << 1;
        bT[q][th]     = cb[(size_t)th * HW + q0 + q];
        bT[q][th + 1] = cb[(size_t)(th + 1) * HW + q0 + q];
    }
    for (int i = tid; i < HW; i += 512) a2s[i] = a2[(size_t)n * HW + i];
    __syncthreads();
    int w = tid >> 6, lane = tid & 63, lm = lane & 15, lg = lane >> 4;
    f16x8 b0 = *(const f16x8*)&bT[w * 16 + lm][lg * 8];
    f16x8 b1 = *(const f16x8*)&bT[w * 16 + lm][32 + lg * 8];
    float bqv = bq[(size_t)n * HW + q0 + w * 16 + lm];
    float m = -3e38f, l = 0.f;
    for (int pf = 0; pf < 64; pf++) {
        f16x8 a0 = *(const f16x8*)(cb + (size_t)(pf * 16 + lm) * S + lg * 8);
        f16x8 a1 = *(const f16x8*)(cb + (size_t)(pf * 16 + lm) * S + 32 + lg * 8);
        f32x4 sg = {};
        sg = MFMA(a0, b0, sg);
        sg = MFMA(a1, b1, sg);
        float sc[4];
        float fm = -3e38f;
        for (int rr = 0; rr < 4; rr++) {
            float av = a2s[pf * 16 + lg * 4 + rr];
            sc[rr] = av * bqv * sg[rr];
            fm = fmaxf(fm, sc[rr]);
        }
        fm = fmaxf(fm, __shfl_xor(fm, 16));
        fm = fmaxf(fm, __shfl_xor(fm, 32));
        float fl = 0.f;
        for (int rr = 0; rr < 4; rr++) fl += EXP2(sc[rr] - fm);
        fl += __shfl_xor(fl, 16);
        fl += __shfl_xor(fl, 32);
        float nm = fmaxf(m, fm);
        l = l * EXP2(m - nm) + fl * EXP2(fm - nm);
        m = nm;
    }
    if (lg == 0) {
        Ms2[(size_t)n * HW + q0 + w * 16 + lm] = m;
        iZs[(size_t)n * HW + q0 + w * 16 + lm] = 1.f / l;
    }
}

// ---------- fused: sigma tile -> weights -> seg_sim (q-tile 64, 2 blocks/CU) ----------
__global__ void __launch_bounds__(512) k_fused(const f16* segf, const f16* segc,
        const float* dp2, const float* e_, const float* a2, const float* bq,
        const float* Mc2, const float* iZc, const float* Ms2, const float* iZs,
        f16* simT) {
    int n = blockIdx.y, q0 = blockIdx.x * 64;
    __shared__ f16 bT[64][72];      // segc^T tile [q][t]
    __shared__ f16 wT[64][72];      // weight tile [q][p - p0]
    __shared__ float dp2s[HW], a2s[HW];
    const f16* cb = segc + (size_t)n * S * HW;
    const f16* sb = segf + (size_t)n * C * HW;
    int tid = threadIdx.x;
    for (int idx = tid; idx < 64 * (S / 2); idx += 512) {
        int q = idx & 63, th = (idx >> 6) << 1;
        bT[q][th]     = cb[(size_t)th * HW + q0 + q];
        bT[q][th + 1] = cb[(size_t)(th + 1) * HW + q0 + q];
    }
    for (int i = tid; i < HW; i += 512) {
        dp2s[i] = dp2[(size_t)n * HW + i];
        a2s[i]  = a2[(size_t)n * HW + i];
    }
    __syncthreads();
    int w = tid >> 6, lane = tid & 63, lm = lane & 15, lg = lane >> 4;
    int pf = w & 3;       // stage-1 p-frag
    int qg = w >> 2;      // stage-1 q-half (32 q)
    // stage-1 b fragments + per-q scalars for this wave's 2 q-frags
    f16x8 b1[2][2];
    float ev[2], bqv[2], mcv[2], izcv[2], msv[2], izsv[2];
    for (int j = 0; j < 2; j++) {
        int ql = qg * 32 + j * 16 + lm;
        b1[j][0] = *(const f16x8*)&bT[ql][lg * 8];
        b1[j][1] = *(const f16x8*)&bT[ql][32 + lg * 8];
        size_t gq = (size_t)n * HW + q0 + ql;
        ev[j] = e_[gq];  bqv[j] = bq[gq];
        mcv[j] = Mc2[gq]; izcv[j] = iZc[gq];
        msv[j] = Ms2[gq]; izsv[j] = iZs[gq];
    }
    f32x4 acc[2][4] = {};   // 32 c-rows (w*32) x 64 q
    for (int chk = 0; chk < 16; chk++) {
        int p0 = chk * 64;
        f16x8 sa0 = *(const f16x8*)(cb + (size_t)(p0 + pf * 16 + lm) * S + lg * 8);
        f16x8 sa1 = *(const f16x8*)(cb + (size_t)(p0 + pf * 16 + lm) * S + 32 + lg * 8);
        float d2r[4], avr[4];
        for (int rr = 0; rr < 4; rr++) {
            d2r[rr] = dp2s[p0 + pf * 16 + lg * 4 + rr];
            avr[rr] = a2s[p0 + pf * 16 + lg * 4 + rr];
        }
        for (int j = 0; j < 2; j++) {
            f32x4 sg = {};
            sg = MFMA(sa0, b1[j][0], sg);
            sg = MFMA(sa1, b1[j][1], sg);
            float wgt[4];
            for (int rr = 0; rr < 4; rr++) {
                float wc  = EXP2(d2r[rr] * ev[j] - mcv[j]) * izcv[j];
                float wsv = EXP2(avr[rr] * bqv[j] * sg[rr] - msv[j]) * izsv[j];
                wgt[rr] = wc + wsv;
            }
            int ql = qg * 32 + j * 16 + lm;
            int pp = pf * 16 + lg * 4;
            union { f16 h[2]; unsigned u; } c0u, c1u;
            c0u.h[0] = (f16)wgt[0]; c0u.h[1] = (f16)wgt[1];
            c1u.h[0] = (f16)wgt[2]; c1u.h[1] = (f16)wgt[3];
            *(unsigned*)&wT[ql][pp]     = c0u.u;
            *(unsigned*)&wT[ql][pp + 2] = c1u.u;
        }
        __syncthreads();
        f16x8 a2f[2][2], b2f[4][2];
        for (int cf = 0; cf < 2; cf++) {
            int crow = w * 32 + cf * 16 + lm;
            a2f[cf][0] = *(const f16x8*)(sb + (size_t)crow * HW + p0 + lg * 8);
            a2f[cf][1] = *(const f16x8*)(sb + (size_t)crow * HW + p0 + 32 + lg * 8);
        }
        for (int qf = 0; qf < 4; qf++) {
            int ql = qf * 16 + lm;
            b2f[qf][0] = *(const f16x8*)&wT[ql][lg * 8];
            b2f[qf][1] = *(const f16x8*)&wT[ql][32 + lg * 8];
        }
        for (int cf = 0; cf < 2; cf++)
            for (int qf = 0; qf < 4; qf++) {
                acc[cf][qf] = MFMA(a2f[cf][0], b2f[qf][0], acc[cf][qf]);
                acc[cf][qf] = MFMA(a2f[cf][1], b2f[qf][1], acc[cf][qf]);
            }
        __syncthreads();
    }
    for (int cf = 0; cf < 2; cf++)
        for (int qf = 0; qf < 4; qf++) {
            int crow = w * 32 + cf * 16 + lg * 4;
            size_t qrow = (size_t)n * HW + q0 + qf * 16 + lm;
            union { f16 h[2]; unsigned u; } c0u, c1u;
            c0u.h[0] = (f16)acc[cf][qf][0]; c0u.h[1] = (f16)acc[cf][qf][1];
            c1u.h[0] = (f16)acc[cf][qf][2]; c1u.h[1] = (f16)acc[cf][qf][3];
            *(unsigned*)(simT + qrow * C + crow)     = c0u.u;
            *(unsigned*)(simT + qrow * C + crow + 2) = c1u.u;
        }
}

// ---------- out = relu(Wg @ seg_sim + bg) + 2*seg_ori (reads f16 seg copy) ----------
__global__ void __launch_bounds__(512) k_out(const f16* Wgf, const f16* simT,
        const float* bg, const f16* segf, float* out) {
    int n = blockIdx.y, q0 = blockIdx.x * 128;
    int tid = threadIdx.x, w = tid >> 6, lane = tid & 63, lm = lane & 15, lg = lane >> 4;
    int ow = (w & 3) * 64, qh = (w >> 2) * 64;
    f32x4 acc[4][4] = {};
    for (int ck = 0; ck < 8; ck++) {
        int c0 = ck * 32;
        f16x8 af[4], bf[4];
        for (int of = 0; of < 4; of++)
            af[of] = *(const f16x8*)(Wgf + (size_t)(ow + of * 16 + lm) * C + c0 + lg * 8);
        for (int qf = 0; qf < 4; qf++)
            bf[qf] = *(const f16x8*)(simT + ((size_t)n * HW + q0 + qh + qf * 16 + lm) * C + c0 + lg * 8);
        for (int of = 0; of < 4; of++)
            for (int qf = 0; qf < 4; qf++)
                acc[of][qf] = MFMA(af[of], bf[qf], acc[of][qf]);
    }
    for (int of = 0; of < 4; of++)
        for (int rr = 0; rr < 4; rr++) {
            int o = ow + of * 16 + lg * 4 + rr;
            float bgv = bg[o];
            for (int qf = 0; qf < 4; qf++) {
                int q = q0 + qh + qf * 16 + lm;
                size_t ix = ((size_t)n * C + o) * HW + q;
                out[ix] = fmaxf(acc[of][qf][rr] + bgv, 0.f) + 2.f * (float)segf[ix];
            }
        }
}

extern "C" void kernel_launch(void* const* d_in, const int* in_sizes, int n_in,
                              void* d_out, int out_size, void* d_ws, size_t ws_size,
                              hipStream_t stream) {
    const float* seg  = (const float*)d_in[0];
    const float* edge = (const float*)d_in[1];
    const float* Ws1  = (const float*)d_in[2];
    const float* bs1  = (const float*)d_in[3];
    const float* Ws11 = (const float*)d_in[4];
    const float* bs11 = (const float*)d_in[5];
    const float* Wmlp = (const float*)d_in[6];
    const float* bmlp = (const float*)d_in[7];
    const float* ws2  = (const float*)d_in[8];
    const float* bs2  = (const float*)d_in[9];
    const float* ws3  = (const float*)d_in[10];
    const float* bs3  = (const float*)d_in[11];
    const float* Wg   = (const float*)d_in[12];
    const float* bg   = (const float*)d_in[13];
    float* out = (float*)d_out;
    char* wsb = (char*)d_ws;

    f16*   segf   = (f16*)(wsb);                   // 16777216 B
    f16*   segc   = (f16*)(wsb + 16777216);        //  4194304 B
    f16*   segs16 = (f16*)(wsb + 20971520);        //  4194304 B
    f16*   simT   = (f16*)(wsb + 25165824);        // 16777216 B
    f16*   Wf     = (f16*)(wsb + 41943040);        //    65536 B
    f16*   Wgf    = (f16*)(wsb + 42008576);        //   131072 B
    float* mean   = (float*)(wsb + 42139648);      //    32768 B
    float* chat   = (float*)(wsb + 42172416);      //     8192 B
    float* dp2    = (float*)(wsb + 42180608);      //   131072 B
    float* e_     = (float*)(wsb + 42311680);
    float* a2     = (float*)(wsb + 42442752);
    float* bq     = (float*)(wsb + 42573824);
    float* Mc2    = (float*)(wsb + 42704896);
    float* iZc    = (float*)(wsb + 42835968);
    float* Ms2    = (float*)(wsb + 42967040);
    float* iZs    = (float*)(wsb + 43098112);
    float* dpmm   = (float*)(wsb + 43229184);      //      256 B

    k_prep<<<256, 256, 0, stream>>>(Ws1, Ws11, Wg, Wf, Wgf);
    k_pool<<<128, 256, 0, stream>>>(seg, edge, segf, a2, bq, ws2, bs2, ws3, bs3);
    k_mean<<<8192, 256, 0, stream>>>(segf, mean);
    k_chatt<<<32, 64, 0, stream>>>(mean, Wmlp, bmlp, chat);
    k_proj<<<dim3(16, 32), 256, 0, stream>>>(segf, Wf, bs1, bs11, segs16, segc);
    k_dp<<<32, 256, 0, stream>>>(segs16, chat, dp2, e_, dpmm);
    k_zc<<<128, 256, 0, stream>>>(dp2, e_, dpmm, Mc2, iZc);
    k_sstats<<<dim3(8, 32), 512, 0, stream>>>(segc, a2, bq, Ms2, iZs);
    k_fused<<<dim3(16, 32), 512, 0, stream>>>(segf, segc, dp2, e_, a2, bq,
                                              Mc2, iZc, Ms2, iZs, simT);
    k_out<<<dim3(8, 32), 512, 0, stream>>>(Wgf, simT, bg, segf, out);
}

// Round 4
// 318.986 us; speedup vs baseline: 1.1342x; 1.0862x over previous
//
#include <hip/hip_runtime.h>

#define N 32
#define C 256
#define HW 1024
#define S 64
#define LOG2E 1.4426950408889634f

typedef _Float16 f16;
typedef _Float16 f16x8 __attribute__((ext_vector_type(8)));
typedef float f32x4 __attribute__((ext_vector_type(4)));

#define MFMA(a, b, c) __builtin_amdgcn_mfma_f32_16x16x32_f16(a, b, c, 0, 0, 0)
#define EXP2(x) exp2f(x)

// ---------- weight conversion ----------
__global__ void k_prep(const float* Ws1, const float* Ws11, const float* Wg,
                       f16* Wf, f16* Wgf) {
    int i = blockIdx.x * 256 + threadIdx.x;   // grid covers 65536
    if (i < S * C) { Wf[i] = (f16)Ws1[i]; Wf[S * C + i] = (f16)Ws11[i]; }
    Wgf[i] = (f16)Wg[i];
}

// ---------- pool pass 1: float4 stream, partial maxes, fused mean ----------
__global__ void __launch_bounds__(256) k_pool1(const float* seg, const float* edge,
        f16* segf, float* pms, float* pme, float* mean) {
    int n = blockIdx.x, cg = blockIdx.y;          // grid (32, 8)
    int t = threadIdx.x, w = t >> 6, lane = t & 63;
    int p4 = (lane << 2) + (w << 8);              // wave w covers p [w*256, +256)
    size_t base = (size_t)n * C * HW;
    float4 ms = make_float4(-3e38f, -3e38f, -3e38f, -3e38f);
    float4 me = ms;
    __shared__ float psum[4][32];
    for (int ci = 0; ci < 32; ci++) {
        int c = cg * 32 + ci;
        size_t off = base + (size_t)c * HW + p4;
        float4 s = *(const float4*)(seg + off);
        float4 e = *(const float4*)(edge + off);
        union { f16 h[4]; unsigned long long u; } pk;
        pk.h[0] = (f16)s.x; pk.h[1] = (f16)s.y; pk.h[2] = (f16)s.z; pk.h[3] = (f16)s.w;
        *(unsigned long long*)(segf + off) = pk.u;
        ms.x = fmaxf(ms.x, s.x); ms.y = fmaxf(ms.y, s.y);
        ms.z = fmaxf(ms.z, s.z); ms.w = fmaxf(ms.w, s.w);
        me.x = fmaxf(me.x, s.x * e.x); me.y = fmaxf(me.y, s.y * e.y);
        me.z = fmaxf(me.z, s.z * e.z); me.w = fmaxf(me.w, s.w * e.w);
        float sm = s.x + s.y + s.z + s.w;
        for (int o = 32; o; o >>= 1) sm += __shfl_down(sm, o);
        if (lane == 0) psum[w][ci] = sm;
    }
    __syncthreads();
    if (t < 32)
        mean[n * C + cg * 32 + t] =
            (psum[0][t] + psum[1][t] + psum[2][t] + psum[3][t]) * (1.0f / HW);
    size_t pb = ((size_t)n * 8 + cg) * HW + p4;
    *(float4*)(pms + pb) = ms;
    *(float4*)(pme + pb) = me;
}

// ---------- pool pass 2: reduce 8 partials -> a2, bq ----------
__global__ void k_pool2(const float* pms, const float* pme, float* a2, float* bq,
                        const float* ws2, const float* bs2,
                        const float* ws3, const float* bs3) {
    int n = blockIdx.x, t = threadIdx.x;
    int p4 = t << 2;
    float4 ms = make_float4(-3e38f, -3e38f, -3e38f, -3e38f);
    float4 me = ms;
    for (int cg = 0; cg < 8; cg++) {
        size_t pb = ((size_t)n * 8 + cg) * HW + p4;
        float4 a = *(const float4*)(pms + pb);
        float4 b = *(const float4*)(pme + pb);
        ms.x = fmaxf(ms.x, a.x); ms.y = fmaxf(ms.y, a.y);
        ms.z = fmaxf(ms.z, a.z); ms.w = fmaxf(ms.w, a.w);
        me.x = fmaxf(me.x, b.x); me.y = fmaxf(me.y, b.y);
        me.z = fmaxf(me.z, b.z); me.w = fmaxf(me.w, b.w);
    }
    float w3 = ws3[0], b3 = bs3[0], w2 = ws2[0], b2 = bs2[0];
    float4 av, bv;
    av.x = (me.x * w3 + b3) * LOG2E; av.y = (me.y * w3 + b3) * LOG2E;
    av.z = (me.z * w3 + b3) * LOG2E; av.w = (me.w * w3 + b3) * LOG2E;
    bv.x = ms.x * w2 + b2; bv.y = ms.y * w2 + b2;
    bv.z = ms.z * w2 + b2; bv.w = ms.w * w2 + b2;
    *(float4*)(a2 + (size_t)n * HW + p4) = av;
    *(float4*)(bq + (size_t)n * HW + p4) = bv;
}

// ---------- ch_att = relu(mean @ Wmlp^T + bmlp) ----------
__global__ void k_chatt(const float* mean, const float* Wmlp, const float* bmlp,
                        float* chat) {
    int n = blockIdx.x, s = threadIdx.x;
    __shared__ float m[C];
    for (int i = s; i < C; i += 64) m[i] = mean[n * C + i];
    __syncthreads();
    float acc = 0.f;
    const float* wr = Wmlp + (size_t)s * C;
    for (int c = 0; c < C; c++) acc += m[c] * wr[c];
    chat[n * S + s] = fmaxf(acc + bmlp[s], 0.f);
}

// ---------- projections: seg_s (rows 0..63) & seg_c (rows 64..127) ----------
__global__ void __launch_bounds__(256) k_proj(const f16* segf, const f16* Wf,
        const float* bs1, const float* bs11, f16* segs16, f16* segc) {
    int n = blockIdx.x;                 // n-major grid (32, 16)
    int q0 = blockIdx.y * 64;
    __shared__ f16 sT[64][264];   // [q][c]
    const f16* sb = segf + (size_t)n * C * HW + q0;
    int tid = threadIdx.x;
    for (int idx = tid; idx < 64 * (C / 2); idx += 256) {
        int q = idx & 63, cc = (idx >> 6) << 1;
        sT[q][cc]     = sb[(size_t)cc * HW + q];
        sT[q][cc + 1] = sb[(size_t)(cc + 1) * HW + q];
    }
    __syncthreads();
    int lane = tid & 63, wv = tid >> 6;
    int lm = lane & 15, lg = lane >> 4;
    f32x4 acc[2][4] = {};
    for (int ck = 0; ck < 8; ck++) {
        int c0 = ck * 32;
        f16x8 a0 = *(const f16x8*)(Wf + (size_t)(wv * 32 + lm) * C + c0 + lg * 8);
        f16x8 a1 = *(const f16x8*)(Wf + (size_t)(wv * 32 + 16 + lm) * C + c0 + lg * 8);
        for (int j = 0; j < 4; j++) {
            f16x8 b = *(const f16x8*)&sT[j * 16 + lm][c0 + lg * 8];
            acc[0][j] = MFMA(a0, b, acc[0][j]);
            acc[1][j] = MFMA(a1, b, acc[1][j]);
        }
    }
    for (int i = 0; i < 2; i++)
        for (int rr = 0; rr < 4; rr++) {
            int row = wv * 32 + i * 16 + lg * 4 + rr;
            float bias = (row < S) ? bs1[row] : bs11[row - S];
            for (int j = 0; j < 4; j++) {
                int q = q0 + j * 16 + lm;
                float v = acc[i][j][rr] + bias;
                if (row < S) segs16[((size_t)n * S + row) * HW + q] = (f16)v;
                else         segc[((size_t)n * S + (row - S)) * HW + q] = (f16)v;
            }
        }
}

// ---------- dp2[p], e[q], partial dp2 max/min; grid (32, 8) ----------
__global__ void __launch_bounds__(256) k_dp(const f16* segs16, const float* chat,
        float* dp2, float* e_, float* dpmm2) {
    int n = blockIdx.x, g = blockIdx.y, t = threadIdx.x;
    __shared__ float cA[S];
    __shared__ float rmx[2], rmn[2];
    if (t < S) cA[t] = chat[n * S + t];
    __syncthreads();
    const f16* ss = segs16 + (size_t)n * S * HW;
    if (t < 128) {
        int p = g * 128 + t;
        // theta[p,tt] = seg_s[p>>4][64*(p&15)+tt]  (flat reshape!)
        const f16* bb = ss + (size_t)(p >> 4) * HW + ((p & 15) << 6);
        float acc = 0.f;
        for (int tt = 0; tt < S; tt += 8) {
            f16x8 v = *(const f16x8*)(bb + tt);
            for (int j = 0; j < 8; j++) acc += (float)v[j] * cA[tt + j];
        }
        float d2 = acc * LOG2E;
        dp2[(size_t)n * HW + p] = d2;
        float mx = d2, mn = d2;
        for (int o = 32; o; o >>= 1) {
            mx = fmaxf(mx, __shfl_down(mx, o));
            mn = fminf(mn, __shfl_down(mn, o));
        }
        if ((t & 63) == 0) { rmx[t >> 6] = mx; rmn[t >> 6] = mn; }
    } else {
        int q = g * 128 + (t - 128);
        float acc = 0.f;
        for (int tt = 0; tt < S; tt++) acc += cA[tt] * (float)ss[(size_t)tt * HW + q];
        e_[(size_t)n * HW + q] = acc;
    }
    __syncthreads();
    if (t == 0) {
        dpmm2[(n * 8 + g) * 2]     = fmaxf(rmx[0], rmx[1]);
        dpmm2[(n * 8 + g) * 2 + 1] = fminf(rmn[0], rmn[1]);
    }
}

// ---------- sim_c softmax stats (rank-1 logits); grid (32, 8), 2 thr/q ----------
__global__ void __launch_bounds__(256) k_zc(const float* dp2, const float* e_,
        const float* dpmm2, float* Mc2, float* iZc) {
    int n = blockIdx.x, g = blockIdx.y, t = threadIdx.x;
    __shared__ float d[HW];
    for (int i = t; i < HW; i += 256) d[i] = dp2[(size_t)n * HW + i];
    float mx = -3e38f, mn = 3e38f;
    for (int j = 0; j < 8; j++) {
        mx = fmaxf(mx, dpmm2[(n * 8 + j) * 2]);
        mn = fminf(mn, dpmm2[(n * 8 + j) * 2 + 1]);
    }
    __syncthreads();
    int q = g * 128 + (t >> 1);
    float eq = e_[(size_t)n * HW + q];
    float m = (eq > 0.f) ? eq * mx : eq * mn;
    float z = 0.f;
    for (int p = (t & 1); p < HW; p += 2) z += EXP2(d[p] * eq - m);
    z += __shfl_xor(z, 1);
    if ((t & 1) == 0) {
        Mc2[(size_t)n * HW + q] = m;
        iZc[(size_t)n * HW + q] = 1.f / z;
    }
}

// ---------- sim_s softmax stats: online (m,l), 2 p-frags/iter; grid (32, 8) ----------
__global__ void __launch_bounds__(512) k_sstats(const f16* segc, const float* a2,
        const float* bq, float* Ms2, float* iZs) {
    int n = blockIdx.x, q0 = blockIdx.y * 128;
    __shared__ f16 bT[128][72];     // [q][t]
    __shared__ float a2s[HW];
    const f16* cb = segc + (size_t)n * S * HW;
    int tid = threadIdx.x;
    for (int idx = tid; idx < 128 * (S / 2); idx += 512) {
        int q = idx & 127, th = (idx >> 7) << 1;
        bT[q][th]     = cb[(size_t)th * HW + q0 + q];
        bT[q][th + 1] = cb[(size_t)(th + 1) * HW + q0 + q];
    }
    for (int i = tid; i < HW; i += 512) a2s[i] = a2[(size_t)n * HW + i];
    __syncthreads();
    int w = tid >> 6, lane = tid & 63, lm = lane & 15, lg = lane >> 4;
    f16x8 b0 = *(const f16x8*)&bT[w * 16 + lm][lg * 8];
    f16x8 b1 = *(const f16x8*)&bT[w * 16 + lm][32 + lg * 8];
    float bqv = bq[(size_t)n * HW + q0 + w * 16 + lm];
    float m = -3e38f, l = 0.f;
    for (int pf = 0; pf < 32; pf++) {
        int pA = pf * 32 + lm;
        f16x8 a0 = *(const f16x8*)(cb + (size_t)pA * S + lg * 8);
        f16x8 a1 = *(const f16x8*)(cb + (size_t)pA * S + 32 + lg * 8);
        f16x8 c0 = *(const f16x8*)(cb + (size_t)(pA + 16) * S + lg * 8);
        f16x8 c1 = *(const f16x8*)(cb + (size_t)(pA + 16) * S + 32 + lg * 8);
        f32x4 sgA = {}, sgB = {};
        sgA = MFMA(a0, b0, sgA); sgA = MFMA(a1, b1, sgA);
        sgB = MFMA(c0, b0, sgB); sgB = MFMA(c1, b1, sgB);
        float sc[8];
        float fm = -3e38f;
        for (int rr = 0; rr < 4; rr++) {
            float avA = a2s[pf * 32 + lg * 4 + rr];
            float avB = a2s[pf * 32 + 16 + lg * 4 + rr];
            sc[rr]     = avA * bqv * sgA[rr];
            sc[rr + 4] = avB * bqv * sgB[rr];
            fm = fmaxf(fm, fmaxf(sc[rr], sc[rr + 4]));
        }
        fm = fmaxf(fm, __shfl_xor(fm, 16));
        fm = fmaxf(fm, __shfl_xor(fm, 32));
        float fl = 0.f;
        for (int rr = 0; rr < 8; rr++) fl += EXP2(sc[rr] - fm);
        fl += __shfl_xor(fl, 16);
        fl += __shfl_xor(fl, 32);
        float nm = fmaxf(m, fm);
        l = l * EXP2(m - nm) + fl * EXP2(fm - nm);
        m = nm;
    }
    if (lg == 0) {
        Ms2[(size_t)n * HW + q0 + w * 16 + lm] = m;
        iZs[(size_t)n * HW + q0 + w * 16 + lm] = 1.f / l;
    }
}

// ---------- fused: sigma -> weights -> seg_sim; dbuf wT, 1 barrier/chunk ----------
__global__ void __launch_bounds__(512, 4) k_fused(const f16* segf, const f16* segc,
        const float* dp2, const float* e_, const float* a2, const float* bq,
        const float* Mc2, const float* iZc, const float* Ms2, const float* iZs,
        f16* simT) {
    int n = blockIdx.x, q0 = blockIdx.y * 64;   // n-major grid (32, 16)
    __shared__ f16 bT[64][72];      // segc^T tile [q][t]
    __shared__ f16 wT[2][64][72];   // double-buffered weight tile [q][p - p0]
    __shared__ float dp2s[HW], a2s[HW];
    const f16* cb = segc + (size_t)n * S * HW;
    const f16* sb = segf + (size_t)n * C * HW;
    int tid = threadIdx.x;
    for (int idx = tid; idx < 64 * (S / 2); idx += 512) {
        int q = idx & 63, th = (idx >> 6) << 1;
        bT[q][th]     = cb[(size_t)th * HW + q0 + q];
        bT[q][th + 1] = cb[(size_t)(th + 1) * HW + q0 + q];
    }
    for (int i = tid; i < HW; i += 512) {
        dp2s[i] = dp2[(size_t)n * HW + i];
        a2s[i]  = a2[(size_t)n * HW + i];
    }
    __syncthreads();
    int w = tid >> 6, lane = tid & 63, lm = lane & 15, lg = lane >> 4;
    int pf = w & 3;       // stage-1 p-frag
    int qg = w >> 2;      // stage-1 q-half (32 q)
    f16x8 b1[2][2];
    float ev[2], bqv[2], mcv[2], izcv[2], msv[2], izsv[2];
    for (int j = 0; j < 2; j++) {
        int ql = qg * 32 + j * 16 + lm;
        b1[j][0] = *(const f16x8*)&bT[ql][lg * 8];
        b1[j][1] = *(const f16x8*)&bT[ql][32 + lg * 8];
        size_t gq = (size_t)n * HW + q0 + ql;
        ev[j] = e_[gq];  bqv[j] = bq[gq];
        mcv[j] = Mc2[gq]; izcv[j] = iZc[gq];
        msv[j] = Ms2[gq]; izsv[j] = iZs[gq];
    }
    f32x4 acc[2][4] = {};   // 32 c-rows (w*32) x 64 q
    for (int chk = 0; chk <= 16; chk++) {
        if (chk < 16) {
            // stage 1 for chunk chk -> wT[chk&1]
            int p0 = chk * 64;
            f16x8 sa0 = *(const f16x8*)(cb + (size_t)(p0 + pf * 16 + lm) * S + lg * 8);
            f16x8 sa1 = *(const f16x8*)(cb + (size_t)(p0 + pf * 16 + lm) * S + 32 + lg * 8);
            float d2r[4], avr[4];
            for (int rr = 0; rr < 4; rr++) {
                d2r[rr] = dp2s[p0 + pf * 16 + lg * 4 + rr];
                avr[rr] = a2s[p0 + pf * 16 + lg * 4 + rr];
            }
            for (int j = 0; j < 2; j++) {
                f32x4 sg = {};
                sg = MFMA(sa0, b1[j][0], sg);
                sg = MFMA(sa1, b1[j][1], sg);
                float wgt[4];
                for (int rr = 0; rr < 4; rr++) {
                    float wc  = EXP2(d2r[rr] * ev[j] - mcv[j]) * izcv[j];
                    float wsv = EXP2(avr[rr] * bqv[j] * sg[rr] - msv[j]) * izsv[j];
                    wgt[rr] = wc + wsv;
                }
                int ql = qg * 32 + j * 16 + lm;
                int pp = pf * 16 + lg * 4;
                union { f16 h[2]; unsigned u; } c0u, c1u;
                c0u.h[0] = (f16)wgt[0]; c0u.h[1] = (f16)wgt[1];
                c1u.h[0] = (f16)wgt[2]; c1u.h[1] = (f16)wgt[3];
                *(unsigned*)&wT[chk & 1][ql][pp]     = c0u.u;
                *(unsigned*)&wT[chk & 1][ql][pp + 2] = c1u.u;
            }
        }
        if (chk > 0) {
            // stage 2 for chunk chk-1 from wT[(chk-1)&1]
            int p0 = (chk - 1) * 64;
            int cur = (chk - 1) & 1;
            f16x8 a2f[2][2];
            for (int cf = 0; cf < 2; cf++) {
                int crow = w * 32 + cf * 16 + lm;
                a2f[cf][0] = *(const f16x8*)(sb + (size_t)crow * HW + p0 + lg * 8);
                a2f[cf][1] = *(const f16x8*)(sb + (size_t)crow * HW + p0 + 32 + lg * 8);
            }
            for (int qf = 0; qf < 4; qf++) {
                int ql = qf * 16 + lm;
                f16x8 bb0 = *(const f16x8*)&wT[cur][ql][lg * 8];
                f16x8 bb1 = *(const f16x8*)&wT[cur][ql][32 + lg * 8];
                for (int cf = 0; cf < 2; cf++) {
                    acc[cf][qf] = MFMA(a2f[cf][0], bb0, acc[cf][qf]);
                    acc[cf][qf] = MFMA(a2f[cf][1], bb1, acc[cf][qf]);
                }
            }
        }
        __syncthreads();
    }
    for (int cf = 0; cf < 2; cf++)
        for (int qf = 0; qf < 4; qf++) {
            int crow = w * 32 + cf * 16 + lg * 4;
            size_t qrow = (size_t)n * HW + q0 + qf * 16 + lm;
            union { f16 h[2]; unsigned u; } c0u, c1u;
            c0u.h[0] = (f16)acc[cf][qf][0]; c0u.h[1] = (f16)acc[cf][qf][1];
            c1u.h[0] = (f16)acc[cf][qf][2]; c1u.h[1] = (f16)acc[cf][qf][3];
            *(unsigned*)(simT + qrow * C + crow)     = c0u.u;
            *(unsigned*)(simT + qrow * C + crow + 2) = c1u.u;
        }
}

// ---------- out = relu(Wg @ seg_sim + bg) + 2*seg_ori (f16 seg copy) ----------
__global__ void __launch_bounds__(512) k_out(const f16* Wgf, const f16* simT,
        const float* bg, const f16* segf, float* out) {
    int n = blockIdx.y, q0 = blockIdx.x * 128;
    int tid = threadIdx.x, w = tid >> 6, lane = tid & 63, lm = lane & 15, lg = lane >> 4;
    int ow = (w & 3) * 64, qh = (w >> 2) * 64;
    f32x4 acc[4][4] = {};
    for (int ck = 0; ck < 8; ck++) {
        int c0 = ck * 32;
        f16x8 af[4], bf[4];
        for (int of = 0; of < 4; of++)
            af[of] = *(const f16x8*)(Wgf + (size_t)(ow + of * 16 + lm) * C + c0 + lg * 8);
        for (int qf = 0; qf < 4; qf++)
            bf[qf] = *(const f16x8*)(simT + ((size_t)n * HW + q0 + qh + qf * 16 + lm) * C + c0 + lg * 8);
        for (int of = 0; of < 4; of++)
            for (int qf = 0; qf < 4; qf++)
                acc[of][qf] = MFMA(af[of], bf[qf], acc[of][qf]);
    }
    for (int of = 0; of < 4; of++)
        for (int rr = 0; rr < 4; rr++) {
            int o = ow + of * 16 + lg * 4 + rr;
            float bgv = bg[o];
            for (int qf = 0; qf < 4; qf++) {
                int q = q0 + qh + qf * 16 + lm;
                size_t ix = ((size_t)n * C + o) * HW + q;
                out[ix] = fmaxf(acc[of][qf][rr] + bgv, 0.f) + 2.f * (float)segf[ix];
            }
        }
}

extern "C" void kernel_launch(void* const* d_in, const int* in_sizes, int n_in,
                              void* d_out, int out_size, void* d_ws, size_t ws_size,
                              hipStream_t stream) {
    const float* seg  = (const float*)d_in[0];
    const float* edge = (const float*)d_in[1];
    const float* Ws1  = (const float*)d_in[2];
    const float* bs1  = (const float*)d_in[3];
    const float* Ws11 = (const float*)d_in[4];
    const float* bs11 = (const float*)d_in[5];
    const float* Wmlp = (const float*)d_in[6];
    const float* bmlp = (const float*)d_in[7];
    const float* ws2  = (const float*)d_in[8];
    const float* bs2  = (const float*)d_in[9];
    const float* ws3  = (const float*)d_in[10];
    const float* bs3  = (const float*)d_in[11];
    const float* Wg   = (const float*)d_in[12];
    const float* bg   = (const float*)d_in[13];
    float* out = (float*)d_out;
    char* wsb = (char*)d_ws;

    f16*   segf   = (f16*)(wsb);                   // 16777216 B
    f16*   segc   = (f16*)(wsb + 16777216);        //  4194304 B
    f16*   segs16 = (f16*)(wsb + 20971520);        //  4194304 B
    f16*   simT   = (f16*)(wsb + 25165824);        // 16777216 B
    // pms/pme overlay the simT region (dead until k_fused writes it)
    float* pms    = (float*)(wsb + 25165824);             // 1 MB
    float* pme    = (float*)(wsb + 25165824 + 1048576);   // 1 MB
    f16*   Wf     = (f16*)(wsb + 41943040);        //    65536 B
    f16*   Wgf    = (f16*)(wsb + 42008576);        //   131072 B
    float* mean   = (float*)(wsb + 42139648);      //    32768 B
    float* chat   = (float*)(wsb + 42172416);      //     8192 B
    float* dp2    = (float*)(wsb + 42180608);      //   131072 B
    float* e_     = (float*)(wsb + 42311680);
    float* a2     = (float*)(wsb + 42442752);
    float* bq     = (float*)(wsb + 42573824);
    float* Mc2    = (float*)(wsb + 42704896);
    float* iZc    = (float*)(wsb + 42835968);
    float* Ms2    = (float*)(wsb + 42967040);
    float* iZs    = (float*)(wsb + 43098112);
    float* dpmm2  = (float*)(wsb + 43229184);      //     2048 B

    k_prep<<<256, 256, 0, stream>>>(Ws1, Ws11, Wg, Wf, Wgf);
    k_pool1<<<dim3(32, 8), 256, 0, stream>>>(seg, edge, segf, pms, pme, mean);
    k_pool2<<<32, 256, 0, stream>>>(pms, pme, a2, bq, ws2, bs2, ws3, bs3);
    k_chatt<<<32, 64, 0, stream>>>(mean, Wmlp, bmlp, chat);
    k_proj<<<dim3(32, 16), 256, 0, stream>>>(segf, Wf, bs1, bs11, segs16, segc);
    k_dp<<<dim3(32, 8), 256, 0, stream>>>(segs16, chat, dp2, e_, dpmm2);
    k_zc<<<dim3(32, 8), 256, 0, stream>>>(dp2, e_, dpmm2, Mc2, iZc);
    k_sstats<<<dim3(32, 8), 512, 0, stream>>>(segc, a2, bq, Ms2, iZs);
    k_fused<<<dim3(32, 16), 512, 0, stream>>>(segf, segc, dp2, e_, a2, bq,
                                              Mc2, iZc, Ms2, iZs, simT);
    k_out<<<dim3(8, 32), 512, 0, stream>>>(Wgf, simT, bg, segf, out);
}

// Round 5
// 283.722 us; speedup vs baseline: 1.2752x; 1.1243x over previous
//
#include <hip/hip_runtime.h>

#define N 32
#define C 256
#define HW 1024
#define S 64
#define LOG2E 1.4426950408889634f

typedef _Float16 f16;
typedef _Float16 f16x4 __attribute__((ext_vector_type(4)));
typedef _Float16 f16x8 __attribute__((ext_vector_type(8)));
typedef float f32x4 __attribute__((ext_vector_type(4)));

#define MFMA(a, b, c) __builtin_amdgcn_mfma_f32_16x16x32_f16(a, b, c, 0, 0, 0)
#define EXP2(x) exp2f(x)

// 8B-aligned LDS f16x8 load (two ds_read_b64, conflict-friendly strides)
__device__ inline f16x8 lds_ld8(const f16* p) {
    f16x4 a = *(const f16x4*)p;
    f16x4 b = *(const f16x4*)(p + 4);
    f16x8 r;
    r[0] = a[0]; r[1] = a[1]; r[2] = a[2]; r[3] = a[3];
    r[4] = b[0]; r[5] = b[1]; r[6] = b[2]; r[7] = b[3];
    return r;
}

// ---------- weight conversion ----------
__global__ void k_prep(const float* Ws1, const float* Ws11, const float* Wg,
                       f16* Wf, f16* Wgf) {
    int i = blockIdx.x * 256 + threadIdx.x;   // grid covers 65536
    if (i < S * C) { Wf[i] = (f16)Ws1[i]; Wf[S * C + i] = (f16)Ws11[i]; }
    Wgf[i] = (f16)Wg[i];
}

// ---------- pool pass 1: float4 stream, partial maxes, fused mean; 4 blk/CU ----------
__global__ void __launch_bounds__(256) k_pool1(const float* seg, const float* edge,
        f16* segf, float* pms, float* pme, float* mean) {
    int n = blockIdx.x, cg = blockIdx.y;          // grid (32, 32), 8 c per block
    int t = threadIdx.x, w = t >> 6, lane = t & 63;
    int p4 = (lane << 2) + (w << 8);
    size_t base = (size_t)n * C * HW;
    float4 ms = make_float4(-3e38f, -3e38f, -3e38f, -3e38f);
    float4 me = ms;
    __shared__ float psum[4][8];
    for (int ci = 0; ci < 8; ci++) {
        int c = cg * 8 + ci;
        size_t off = base + (size_t)c * HW + p4;
        float4 s = *(const float4*)(seg + off);
        float4 e = *(const float4*)(edge + off);
        union { f16 h[4]; unsigned long long u; } pk;
        pk.h[0] = (f16)s.x; pk.h[1] = (f16)s.y; pk.h[2] = (f16)s.z; pk.h[3] = (f16)s.w;
        *(unsigned long long*)(segf + off) = pk.u;
        ms.x = fmaxf(ms.x, s.x); ms.y = fmaxf(ms.y, s.y);
        ms.z = fmaxf(ms.z, s.z); ms.w = fmaxf(ms.w, s.w);
        me.x = fmaxf(me.x, s.x * e.x); me.y = fmaxf(me.y, s.y * e.y);
        me.z = fmaxf(me.z, s.z * e.z); me.w = fmaxf(me.w, s.w * e.w);
        float sm = s.x + s.y + s.z + s.w;
        for (int o = 32; o; o >>= 1) sm += __shfl_down(sm, o);
        if (lane == 0) psum[w][ci] = sm;
    }
    __syncthreads();
    if (t < 8)
        mean[n * C + cg * 8 + t] =
            (psum[0][t] + psum[1][t] + psum[2][t] + psum[3][t]) * (1.0f / HW);
    size_t pb = ((size_t)n * 32 + cg) * HW + p4;
    *(float4*)(pms + pb) = ms;
    *(float4*)(pme + pb) = me;
}

// ---------- pool pass 2: reduce 32 partials -> a2, bq ----------
__global__ void k_pool2(const float* pms, const float* pme, float* a2, float* bq,
                        const float* ws2, const float* bs2,
                        const float* ws3, const float* bs3) {
    int n = blockIdx.x, t = threadIdx.x;
    int p4 = t << 2;
    float4 ms = make_float4(-3e38f, -3e38f, -3e38f, -3e38f);
    float4 me = ms;
    for (int cg = 0; cg < 32; cg++) {
        size_t pb = ((size_t)n * 32 + cg) * HW + p4;
        float4 a = *(const float4*)(pms + pb);
        float4 b = *(const float4*)(pme + pb);
        ms.x = fmaxf(ms.x, a.x); ms.y = fmaxf(ms.y, a.y);
        ms.z = fmaxf(ms.z, a.z); ms.w = fmaxf(ms.w, a.w);
        me.x = fmaxf(me.x, b.x); me.y = fmaxf(me.y, b.y);
        me.z = fmaxf(me.z, b.z); me.w = fmaxf(me.w, b.w);
    }
    float w3 = ws3[0], b3 = bs3[0], w2 = ws2[0], b2 = bs2[0];
    float4 av, bv;
    av.x = (me.x * w3 + b3) * LOG2E; av.y = (me.y * w3 + b3) * LOG2E;
    av.z = (me.z * w3 + b3) * LOG2E; av.w = (me.w * w3 + b3) * LOG2E;
    bv.x = ms.x * w2 + b2; bv.y = ms.y * w2 + b2;
    bv.z = ms.z * w2 + b2; bv.w = ms.w * w2 + b2;
    *(float4*)(a2 + (size_t)n * HW + p4) = av;
    *(float4*)(bq + (size_t)n * HW + p4) = bv;
}

// ---------- ch_att = relu(mean @ Wmlp^T + bmlp) ----------
__global__ void k_chatt(const float* mean, const float* Wmlp, const float* bmlp,
                        float* chat) {
    int n = blockIdx.x, s = threadIdx.x;
    __shared__ float m[C];
    for (int i = s; i < C; i += 64) m[i] = mean[n * C + i];
    __syncthreads();
    float acc = 0.f;
    const float* wr = Wmlp + (size_t)s * C;
    for (int c = 0; c < C; c++) acc += m[c] * wr[c];
    chat[n * S + s] = fmaxf(acc + bmlp[s], 0.f);
}

// ---------- projections: seg_s (rows 0..63) & seg_c (rows 64..127) ----------
__global__ void __launch_bounds__(512) k_proj(const f16* segf, const f16* Wf,
        const float* bs1, const float* bs11, f16* segs16, f16* segc) {
    int n = blockIdx.x;                 // n-major grid (32, 16)
    int q0 = blockIdx.y * 64;
    __shared__ f16 sT[64][260];   // [q][c], stride 260 (8B-aligned rows, 2-way banks)
    const f16* sb = segf + (size_t)n * C * HW + q0;
    int tid = threadIdx.x;
    for (int idx = tid; idx < 64 * 128; idx += 512) {
        int q = idx & 63, cc = (idx >> 6) << 1;
        union { f16 h[2]; unsigned u; } pk;
        pk.h[0] = sb[(size_t)cc * HW + q];
        pk.h[1] = sb[(size_t)(cc + 1) * HW + q];
        *(unsigned*)&sT[q][cc] = pk.u;
    }
    __syncthreads();
    int lane = tid & 63, wv = tid >> 6;
    int lm = lane & 15, lg = lane >> 4;
    f32x4 acc[4] = {};
    for (int ck = 0; ck < 8; ck++) {
        int c0 = ck * 32;
        f16x8 a0 = *(const f16x8*)(Wf + (size_t)(wv * 16 + lm) * C + c0 + lg * 8);
        for (int j = 0; j < 4; j++) {
            f16x8 b = lds_ld8(&sT[j * 16 + lm][c0 + lg * 8]);
            acc[j] = MFMA(a0, b, acc[j]);
        }
    }
    for (int rr = 0; rr < 4; rr++) {
        int row = wv * 16 + lg * 4 + rr;
        float bias = (row < S) ? bs1[row] : bs11[row - S];
        for (int j = 0; j < 4; j++) {
            int q = q0 + j * 16 + lm;
            float v = acc[j][rr] + bias;
            if (row < S) segs16[((size_t)n * S + row) * HW + q] = (f16)v;
            else         segc[((size_t)n * S + (row - S)) * HW + q] = (f16)v;
        }
    }
}

// ---------- dp2[p], e[q], partial dp2 max/min; grid (32, 8) ----------
__global__ void __launch_bounds__(256) k_dp(const f16* segs16, const float* chat,
        float* dp2, float* e_, float* dpmm2) {
    int n = blockIdx.x, g = blockIdx.y, t = threadIdx.x;
    __shared__ float cA[S];
    __shared__ float rmx[2], rmn[2];
    if (t < S) cA[t] = chat[n * S + t];
    __syncthreads();
    const f16* ss = segs16 + (size_t)n * S * HW;
    if (t < 128) {
        int p = g * 128 + t;
        const f16* bb = ss + (size_t)(p >> 4) * HW + ((p & 15) << 6);
        float acc = 0.f;
        for (int tt = 0; tt < S; tt += 8) {
            f16x8 v = *(const f16x8*)(bb + tt);
            for (int j = 0; j < 8; j++) acc += (float)v[j] * cA[tt + j];
        }
        float d2 = acc * LOG2E;
        dp2[(size_t)n * HW + p] = d2;
        float mx = d2, mn = d2;
        for (int o = 32; o; o >>= 1) {
            mx = fmaxf(mx, __shfl_down(mx, o));
            mn = fminf(mn, __shfl_down(mn, o));
        }
        if ((t & 63) == 0) { rmx[t >> 6] = mx; rmn[t >> 6] = mn; }
    } else {
        int q = g * 128 + (t - 128);
        float acc = 0.f;
        for (int tt = 0; tt < S; tt++) acc += cA[tt] * (float)ss[(size_t)tt * HW + q];
        e_[(size_t)n * HW + q] = acc;
    }
    __syncthreads();
    if (t == 0) {
        dpmm2[(n * 8 + g) * 2]     = fmaxf(rmx[0], rmx[1]);
        dpmm2[(n * 8 + g) * 2 + 1] = fminf(rmn[0], rmn[1]);
    }
}

// ---------- sim_c softmax stats; grid (32,16), 4 thr/q ----------
__global__ void __launch_bounds__(256) k_zc(const float* dp2, const float* e_,
        const float* dpmm2, float* Mc2, float* iZc) {
    int n = blockIdx.x, g = blockIdx.y, t = threadIdx.x;
    __shared__ float d[HW];
    for (int i = t; i < HW; i += 256) d[i] = dp2[(size_t)n * HW + i];
    float mx = -3e38f, mn = 3e38f;
    for (int j = 0; j < 8; j++) {
        mx = fmaxf(mx, dpmm2[(n * 8 + j) * 2]);
        mn = fminf(mn, dpmm2[(n * 8 + j) * 2 + 1]);
    }
    __syncthreads();
    int q = g * 64 + (t >> 2);
    float eq = e_[(size_t)n * HW + q];
    float m = (eq > 0.f) ? eq * mx : eq * mn;
    float z = 0.f;
    for (int p = (t & 3); p < HW; p += 4) z += EXP2(d[p] * eq - m);
    z += __shfl_xor(z, 1);
    z += __shfl_xor(z, 2);
    if ((t & 3) == 0) {
        Mc2[(size_t)n * HW + q] = m;
        iZc[(size_t)n * HW + q] = 1.f / z;
    }
}

// ---------- sim_s softmax stats: online (m,l), p split across wave pairs ----------
__global__ void __launch_bounds__(512) k_sstats(const f16* segc, const float* a2,
        const float* bq, float* Ms2, float* iZs) {
    int n = blockIdx.x, q0 = blockIdx.y * 64;   // grid (32, 16)
    __shared__ f16 bT[64][68];     // [q][t], stride 68 (8B-aligned, 2-way banks)
    __shared__ float a2s[HW];
    __shared__ float mred[64][2], lred[64][2];
    const f16* cb = segc + (size_t)n * S * HW;
    int tid = threadIdx.x;
    for (int idx = tid; idx < 64 * 32; idx += 512) {
        int q = idx & 63, th = (idx >> 6) << 1;
        union { f16 h[2]; unsigned u; } pk;
        pk.h[0] = cb[(size_t)th * HW + q0 + q];
        pk.h[1] = cb[(size_t)(th + 1) * HW + q0 + q];
        *(unsigned*)&bT[q][th] = pk.u;
    }
    for (int i = tid; i < HW; i += 512) a2s[i] = a2[(size_t)n * HW + i];
    __syncthreads();
    int w = tid >> 6, lane = tid & 63, lm = lane & 15, lg = lane >> 4;
    int qg = w >> 1, ph = w & 1;
    f16x8 b0 = lds_ld8(&bT[qg * 16 + lm][lg * 8]);
    f16x8 b1 = lds_ld8(&bT[qg * 16 + lm][32 + lg * 8]);
    float bqv = bq[(size_t)n * HW + q0 + qg * 16 + lm];
    float m = -3e38f, l = 0.f;
    for (int it = 0; it < 16; it++) {
        int pb = ph * 512 + it * 32;
        f16x8 a0 = *(const f16x8*)(cb + (size_t)(pb + lm) * S + lg * 8);
        f16x8 a1 = *(const f16x8*)(cb + (size_t)(pb + lm) * S + 32 + lg * 8);
        f16x8 c0 = *(const f16x8*)(cb + (size_t)(pb + 16 + lm) * S + lg * 8);
        f16x8 c1 = *(const f16x8*)(cb + (size_t)(pb + 16 + lm) * S + 32 + lg * 8);
        f32x4 sgA = {}, sgB = {};
        sgA = MFMA(a0, b0, sgA); sgA = MFMA(a1, b1, sgA);
        sgB = MFMA(c0, b0, sgB); sgB = MFMA(c1, b1, sgB);
        float sc[8];
        float fm = -3e38f;
        for (int rr = 0; rr < 4; rr++) {
            float avA = a2s[pb + lg * 4 + rr];
            float avB = a2s[pb + 16 + lg * 4 + rr];
            sc[rr]     = avA * bqv * sgA[rr];
            sc[rr + 4] = avB * bqv * sgB[rr];
            fm = fmaxf(fm, fmaxf(sc[rr], sc[rr + 4]));
        }
        fm = fmaxf(fm, __shfl_xor(fm, 16));
        fm = fmaxf(fm, __shfl_xor(fm, 32));
        float fl = 0.f;
        for (int rr = 0; rr < 8; rr++) fl += EXP2(sc[rr] - fm);
        fl += __shfl_xor(fl, 16);
        fl += __shfl_xor(fl, 32);
        float nm = fmaxf(m, fm);
        l = l * EXP2(m - nm) + fl * EXP2(fm - nm);
        m = nm;
    }
    if (lg == 0) { mred[qg * 16 + lm][ph] = m; lred[qg * 16 + lm][ph] = l; }
    __syncthreads();
    if (tid < 64) {
        float m0 = mred[tid][0], m1 = mred[tid][1];
        float M = fmaxf(m0, m1);
        float L = lred[tid][0] * EXP2(m0 - M) + lred[tid][1] * EXP2(m1 - M);
        Ms2[(size_t)n * HW + q0 + tid] = M;
        iZs[(size_t)n * HW + q0 + tid] = 1.f / L;
    }
}

// ---------- fused: sigma -> weights -> seg_sim; BK=128, dbuf wT ----------
__global__ void __launch_bounds__(512, 4) k_fused(const f16* segf, const f16* segc,
        const float* dp2, const float* e_, const float* a2, const float* bq,
        const float* Mc2, const float* iZc, const float* Ms2, const float* iZs,
        f16* simT) {
    int n = blockIdx.x, q0 = blockIdx.y * 64;   // n-major grid (32, 16)
    __shared__ f16 bT[64][68];        // segc^T tile [q][t]
    __shared__ f16 wT[2][64][132];    // dbuf weight tile [q][p_local], stride 132
    __shared__ float dp2s[HW], a2s[HW];
    const f16* cb = segc + (size_t)n * S * HW;
    const f16* sb = segf + (size_t)n * C * HW;
    int tid = threadIdx.x;
    for (int idx = tid; idx < 64 * 32; idx += 512) {
        int q = idx & 63, th = (idx >> 6) << 1;
        union { f16 h[2]; unsigned u; } pk;
        pk.h[0] = cb[(size_t)th * HW + q0 + q];
        pk.h[1] = cb[(size_t)(th + 1) * HW + q0 + q];
        *(unsigned*)&bT[q][th] = pk.u;
    }
    for (int i = tid; i < HW; i += 512) {
        dp2s[i] = dp2[(size_t)n * HW + i];
        a2s[i]  = a2[(size_t)n * HW + i];
    }
    __syncthreads();
    int w = tid >> 6, lane = tid & 63, lm = lane & 15, lg = lane >> 4;
    // per-q scalars for the 4 q-frags (stage 1 covers all 64 q per wave)
    float ev[4], bqv[4], mcv[4], izcv[4], msv[4], izsv[4];
    for (int j = 0; j < 4; j++) {
        size_t gq = (size_t)n * HW + q0 + j * 16 + lm;
        ev[j] = e_[gq];  bqv[j] = bq[gq];
        mcv[j] = Mc2[gq]; izcv[j] = iZc[gq];
        msv[j] = Ms2[gq]; izsv[j] = iZs[gq];
    }
    f32x4 acc[2][4] = {};   // 32 c-rows (w*32) x 64 q
    for (int chk = 0; chk <= 8; chk++) {
        if (chk < 8) {
            // stage 1 for chunk chk (128 p) -> wT[chk&1]; wave w does p_local w*16..+16
            int p0 = chk * 128;
            int prow = p0 + w * 16 + lm;
            f16x8 sa0 = *(const f16x8*)(cb + (size_t)prow * S + lg * 8);
            f16x8 sa1 = *(const f16x8*)(cb + (size_t)prow * S + 32 + lg * 8);
            float d2r[4], avr[4];
            for (int rr = 0; rr < 4; rr++) {
                d2r[rr] = dp2s[p0 + w * 16 + lg * 4 + rr];
                avr[rr] = a2s[p0 + w * 16 + lg * 4 + rr];
            }
            for (int j = 0; j < 4; j++) {
                f16x8 bb0 = lds_ld8(&bT[j * 16 + lm][lg * 8]);
                f16x8 bb1 = lds_ld8(&bT[j * 16 + lm][32 + lg * 8]);
                f32x4 sg = {};
                sg = MFMA(sa0, bb0, sg);
                sg = MFMA(sa1, bb1, sg);
                float wgt[4];
                for (int rr = 0; rr < 4; rr++) {
                    float wc  = EXP2(d2r[rr] * ev[j] - mcv[j]) * izcv[j];
                    float wsv = EXP2(avr[rr] * bqv[j] * sg[rr] - msv[j]) * izsv[j];
                    wgt[rr] = wc + wsv;
                }
                int ql = j * 16 + lm;
                int pp = w * 16 + lg * 4;
                union { f16 h[2]; unsigned u; } c0u, c1u;
                c0u.h[0] = (f16)wgt[0]; c0u.h[1] = (f16)wgt[1];
                c1u.h[0] = (f16)wgt[2]; c1u.h[1] = (f16)wgt[3];
                *(unsigned*)&wT[chk & 1][ql][pp]     = c0u.u;
                *(unsigned*)&wT[chk & 1][ql][pp + 2] = c1u.u;
            }
        }
        if (chk > 0) {
            // stage 2 for chunk chk-1 from wT[(chk-1)&1]; K = 128
            int p0 = (chk - 1) * 128;
            int cur = (chk - 1) & 1;
            for (int ks = 0; ks < 4; ks++) {
                f16x8 a2f[2];
                for (int cf = 0; cf < 2; cf++) {
                    int crow = w * 32 + cf * 16 + lm;
                    a2f[cf] = *(const f16x8*)(sb + (size_t)crow * HW + p0 + ks * 32 + lg * 8);
                }
                for (int qf = 0; qf < 4; qf++) {
                    f16x8 bb = lds_ld8(&wT[cur][qf * 16 + lm][ks * 32 + lg * 8]);
                    acc[0][qf] = MFMA(a2f[0], bb, acc[0][qf]);
                    acc[1][qf] = MFMA(a2f[1], bb, acc[1][qf]);
                }
            }
        }
        __syncthreads();
    }
    for (int cf = 0; cf < 2; cf++)
        for (int qf = 0; qf < 4; qf++) {
            int crow = w * 32 + cf * 16 + lg * 4;
            size_t qrow = (size_t)n * HW + q0 + qf * 16 + lm;
            union { f16 h[2]; unsigned u; } c0u, c1u;
            c0u.h[0] = (f16)acc[cf][qf][0]; c0u.h[1] = (f16)acc[cf][qf][1];
            c1u.h[0] = (f16)acc[cf][qf][2]; c1u.h[1] = (f16)acc[cf][qf][3];
            *(unsigned*)(simT + qrow * C + crow)     = c0u.u;
            *(unsigned*)(simT + qrow * C + crow + 2) = c1u.u;
        }
}

// ---------- out = relu(Wg @ seg_sim + bg) + 2*seg_ori (f16 seg copy) ----------
__global__ void __launch_bounds__(512) k_out(const f16* Wgf, const f16* simT,
        const float* bg, const f16* segf, float* out) {
    int n = blockIdx.x, q0 = blockIdx.y * 64;   // n-major grid (32, 16)
    int tid = threadIdx.x, w = tid >> 6, lane = tid & 63, lm = lane & 15, lg = lane >> 4;
    int ow = (w & 3) * 64, qh = (w >> 2) * 32;
    f32x4 acc[4][2] = {};
    for (int ck = 0; ck < 8; ck++) {
        int c0 = ck * 32;
        f16x8 af[4], bf[2];
        for (int of = 0; of < 4; of++)
            af[of] = *(const f16x8*)(Wgf + (size_t)(ow + of * 16 + lm) * C + c0 + lg * 8);
        for (int qf = 0; qf < 2; qf++)
            bf[qf] = *(const f16x8*)(simT + ((size_t)n * HW + q0 + qh + qf * 16 + lm) * C + c0 + lg * 8);
        for (int of = 0; of < 4; of++)
            for (int qf = 0; qf < 2; qf++)
                acc[of][qf] = MFMA(af[of], bf[qf], acc[of][qf]);
    }
    for (int of = 0; of < 4; of++)
        for (int rr = 0; rr < 4; rr++) {
            int o = ow + of * 16 + lg * 4 + rr;
            float bgv = bg[o];
            for (int qf = 0; qf < 2; qf++) {
                int q = q0 + qh + qf * 16 + lm;
                size_t ix = ((size_t)n * C + o) * HW + q;
                out[ix] = fmaxf(acc[of][qf][rr] + bgv, 0.f) + 2.f * (float)segf[ix];
            }
        }
}

extern "C" void kernel_launch(void* const* d_in, const int* in_sizes, int n_in,
                              void* d_out, int out_size, void* d_ws, size_t ws_size,
                              hipStream_t stream) {
    const float* seg  = (const float*)d_in[0];
    const float* edge = (const float*)d_in[1];
    const float* Ws1  = (const float*)d_in[2];
    const float* bs1  = (const float*)d_in[3];
    const float* Ws11 = (const float*)d_in[4];
    const float* bs11 = (const float*)d_in[5];
    const float* Wmlp = (const float*)d_in[6];
    const float* bmlp = (const float*)d_in[7];
    const float* ws2  = (const float*)d_in[8];
    const float* bs2  = (const float*)d_in[9];
    const float* ws3  = (const float*)d_in[10];
    const float* bs3  = (const float*)d_in[11];
    const float* Wg   = (const float*)d_in[12];
    const float* bg   = (const float*)d_in[13];
    float* out = (float*)d_out;
    char* wsb = (char*)d_ws;

    f16*   segf   = (f16*)(wsb);                   // 16777216 B
    f16*   segc   = (f16*)(wsb + 16777216);        //  4194304 B
    f16*   segs16 = (f16*)(wsb + 20971520);        //  4194304 B
    f16*   simT   = (f16*)(wsb + 25165824);        // 16777216 B
    // pms/pme overlay the simT region (dead until k_fused writes it)
    float* pms    = (float*)(wsb + 25165824);             // 4 MB
    float* pme    = (float*)(wsb + 29360128);             // 4 MB
    f16*   Wf     = (f16*)(wsb + 41943040);        //    65536 B
    f16*   Wgf    = (f16*)(wsb + 42008576);        //   131072 B
    float* mean   = (float*)(wsb + 42139648);      //    32768 B
    float* chat   = (float*)(wsb + 42172416);      //     8192 B
    float* dp2    = (float*)(wsb + 42180608);      //   131072 B
    float* e_     = (float*)(wsb + 42311680);
    float* a2     = (float*)(wsb + 42442752);
    float* bq     = (float*)(wsb + 42573824);
    float* Mc2    = (float*)(wsb + 42704896);
    float* iZc    = (float*)(wsb + 42835968);
    float* Ms2    = (float*)(wsb + 42967040);
    float* iZs    = (float*)(wsb + 43098112);
    float* dpmm2  = (float*)(wsb + 43229184);      //     2048 B

    k_prep<<<256, 256, 0, stream>>>(Ws1, Ws11, Wg, Wf, Wgf);
    k_pool1<<<dim3(32, 32), 256, 0, stream>>>(seg, edge, segf, pms, pme, mean);
    k_pool2<<<32, 256, 0, stream>>>(pms, pme, a2, bq, ws2, bs2, ws3, bs3);
    k_chatt<<<32, 64, 0, stream>>>(mean, Wmlp, bmlp, chat);
    k_proj<<<dim3(32, 16), 512, 0, stream>>>(segf, Wf, bs1, bs11, segs16, segc);
    k_dp<<<dim3(32, 8), 256, 0, stream>>>(segs16, chat, dp2, e_, dpmm2);
    k_zc<<<dim3(32, 16), 256, 0, stream>>>(dp2, e_, dpmm2, Mc2, iZc);
    k_sstats<<<dim3(32, 16), 512, 0, stream>>>(segc, a2, bq, Ms2, iZs);
    k_fused<<<dim3(32, 16), 512, 0, stream>>>(segf, segc, dp2, e_, a2, bq,
                                              Mc2, iZc, Ms2, iZs, simT);
    k_out<<<dim3(32, 16), 512, 0, stream>>>(Wgf, simT, bg, segf, out);
}